// Round 8
// baseline (249.206 us; speedup 1.0000x reference)
//
#include <hip/hip_runtime.h>
#include <math.h>

#define P_DIM 512
#define H_DIM 512
#define L_DIM 4096
#define M_TR  512
#define NTHR  256
#define QLEN  2048          // outputs per block (grid = H x 2)
#define SEGC  256           // cols per pipeline step
#define RING  1024          // ring cols (bf16), 32KB LDS
#define KRP   576           // padded Kr row stride (zeros at [0,32) and [544,576))
#define NCH   17            // k-chunks of 32 covering [0,544)
#define KRH   4             // h per kr block

typedef __attribute__((ext_vector_type(8))) short short8v;
typedef __attribute__((ext_vector_type(4))) float float4v;

__device__ __forceinline__ unsigned int f2bf(float f) {
    union { float f; unsigned int u; } v; v.f = f;
    return (v.u + 0x7FFFu + ((v.u >> 16) & 1u)) >> 16;   // RNE
}
__device__ __forceinline__ float bf2f(unsigned int b) {
    union { unsigned int u; float f; } v; v.u = b << 16; return v.f;
}

// Kernel A: V[p][m] = lam^m, bf16 pairs (m even|odd packed in uint).
__global__ void vand_kernel(const float* __restrict__ lre, const float* __restrict__ lim,
                            unsigned int* __restrict__ Vre2, unsigned int* __restrict__ Vim2) {
    int idx = blockIdx.x * NTHR + threadIdx.x;
    if (idx >= P_DIM * (M_TR / 2)) return;
    int p = idx >> 8;
    int m0 = (idx & 255) * 2;
    float re = lre[p], im = lim[p];
    float logr = 0.5f * logf(re * re + im * im);
    float th = atan2f(im, re);
    float mag = expf((float)m0 * logr);
    float s, c;
    sincosf((float)m0 * th, &s, &c);
    float vr0 = mag * c, vi0 = mag * s;
    float vr1 = vr0 * re - vi0 * im;
    float vi1 = vr0 * im + vi0 * re;
    Vre2[idx] = f2bf(vr0) | (f2bf(vr1) << 16);
    Vim2[idx] = f2bf(vi0) | (f2bf(vi1) << 16);
}

// Kernel B: Krp[h][32+m] = sum_p Cre*Vre - Cim*Vim (+D at m=0); zero pads.
// 4 h per block: V traffic = 128 blocks x 1MB = 128MB (was 256MB).
__global__ __launch_bounds__(NTHR) void kr_kernel(const float* __restrict__ Cre,
                                                  const float* __restrict__ Cim,
                                                  const float* __restrict__ D,
                                                  const unsigned int* __restrict__ Vre2,
                                                  const unsigned int* __restrict__ Vim2,
                                                  float* __restrict__ Krp) {
    __shared__ float cre_s[KRH][P_DIM];
    __shared__ float cim_s[KRH][P_DIM];
    int t = threadIdx.x;
    int h0 = blockIdx.x * KRH;
#pragma unroll
    for (int k = 0; k < 2 * KRH; ++k) {
        int i = t + k * NTHR;
        int hi = i >> 9, pp = i & (P_DIM - 1);
        cre_s[hi][pp] = Cre[(h0 + hi) * P_DIM + pp];
        cim_s[hi][pp] = Cim[(h0 + hi) * P_DIM + pp];
    }
    __syncthreads();
    float a0[KRH], a1[KRH];
#pragma unroll
    for (int i = 0; i < KRH; ++i) { a0[i] = 0.f; a1[i] = 0.f; }
    for (int p = 0; p < P_DIM; ++p) {
        unsigned int vr = Vre2[p * 256 + t];
        unsigned int vi = Vim2[p * 256 + t];
        float vr0 = bf2f(vr & 0xFFFFu), vr1 = bf2f(vr >> 16);
        float vi0 = bf2f(vi & 0xFFFFu), vi1 = bf2f(vi >> 16);
#pragma unroll
        for (int i = 0; i < KRH; ++i) {
            float cr = cre_s[i][p], ci = cim_s[i][p];
            a0[i] += cr * vr0 - ci * vi0;
            a1[i] += cr * vr1 - ci * vi1;
        }
    }
#pragma unroll
    for (int i = 0; i < KRH; ++i) {
        float v0 = a0[i];
        if (t == 0) v0 += D[h0 + i];
        Krp[(h0 + i) * KRP + 32 + 2 * t]     = v0;
        Krp[(h0 + i) * KRP + 32 + 2 * t + 1] = a1[i];
        if (t < 32) {
            Krp[(h0 + i) * KRP + t] = 0.f;
            Krp[(h0 + i) * KRP + 544 + t] = 0.f;
        }
    }
}

// ---- staging helpers: one 256-col chunk, 16 batches, f32 -> bf16 into swizzled ring
__device__ __forceinline__ void stage_load(const float* __restrict__ u, int h, int CB, int t,
                                           float4* r) {
    int j = t >> 4, coff = (t & 15) << 4;
    int gl = CB + coff;
    if (gl >= 0) {
        const float* p = u + ((long)j * H_DIM + h) * L_DIM + gl;
        r[0] = *(const float4*)p;
        r[1] = *(const float4*)(p + 4);
        r[2] = *(const float4*)(p + 8);
        r[3] = *(const float4*)(p + 12);
    } else {
        r[0] = r[1] = r[2] = r[3] = make_float4(0.f, 0.f, 0.f, 0.f);
    }
}
__device__ __forceinline__ void stage_write(unsigned short (*uls)[RING], int CB, int t,
                                            const float4* r) {
    int j = t >> 4, coff = (t & 15) << 4;
    int slot = (CB + coff) & (RING - 1);
    int ch = slot >> 3;                       // even; thread owns chunks ch, ch+1
    unsigned int pk[8];
#pragma unroll
    for (int k = 0; k < 4; ++k) {
        pk[2 * k]     = f2bf(r[k].x) | (f2bf(r[k].y) << 16);
        pk[2 * k + 1] = f2bf(r[k].z) | (f2bf(r[k].w) << 16);
    }
    int sw = j & 7;
    *(uint4*)&uls[j][(ch ^ sw) << 3]       = *(const uint4*)&pk[0];
    *(uint4*)&uls[j][((ch + 1) ^ sw) << 3] = *(const uint4*)&pk[4];
}

// Kernel C: ring-buffered MFMA Toeplitz convolution, 16x16x32, 4-tile A-reuse,
// swapped operands; epilogue stores pinned to global_store_dwordx4 via inline asm
// (one instruction = one full 128B line; compiler cannot narrow it under pressure).
__global__ __launch_bounds__(NTHR, 4) void conv_mfma(const float* __restrict__ u,
                                                     const float* __restrict__ Krp,
                                                     float* __restrict__ y) {
    __shared__ __align__(16) unsigned short uls[16][RING];   // 32768 B
    __shared__ __align__(16) float trbuf[4][16][32];         // 8192 B  (total 40960)
    int t = threadIdx.x;
    int h = blockIdx.x;
    int Q = blockIdx.y * QLEN;
    int lane = t & 63, w = t >> 6;
    int i16 = lane & 15, hi = lane >> 4;
    int m7 = i16 & 7;
    const long HL = (long)H_DIM * L_DIM;

    // zero ring (finite values everywhere; garbage reads pair with zero-B only)
    {
        unsigned short* flat = &uls[0][0];
        for (int i = t; i < (16 * RING) / 8; i += NTHR)
            *(uint4*)(flat + i * 8) = make_uint4(0u, 0u, 0u, 0u);
    }

    // A fragments (Toeplitz kernel): A[i][k] = Krpad[544 + i - k], k = 32c + 8hi + e
    short8v bfr[NCH];
    {
        const float* kp = Krp + h * KRP + 544 + i16 - 8 * hi;
#pragma unroll
        for (int c = 0; c < NCH; ++c) {
            short8v bv;
#pragma unroll
            for (int e = 0; e < 8; ++e)
                bv[e] = (short)f2bf(kp[-32 * c - e]);
            bfr[c] = bv;
        }
    }
    __syncthreads();

    // prestage 3 chunks: u cols [Q-512, Q+256)
    {
        float4 r0[4], r1[4], r2[4];
        stage_load(u, h, Q - 512, t, r0);
        stage_load(u, h, Q - 256, t, r1);
        stage_load(u, h, Q,       t, r2);
        stage_write(uls, Q - 512, t, r0);
        stage_write(uls, Q - 256, t, r1);
        stage_write(uls, Q,       t, r2);
    }
    __syncthreads();

    for (int s = 0; s < QLEN / SEGC; ++s) {
        int X = Q + s * SEGC;
        float4 rn[4];
        if (s < QLEN / SEGC - 1) stage_load(u, h, X + SEGC, t, rn);

        int W = X + w * 64;
        int base_e = (((W - 512) & (RING - 1)) >> 3) + hi;
        float4v a0 = {0.f,0.f,0.f,0.f}, a1 = {0.f,0.f,0.f,0.f};
        float4v a2 = {0.f,0.f,0.f,0.f}, a3 = {0.f,0.f,0.f,0.f};
#pragma unroll
        for (int c = 0; c <= NCH; ++c) {                      // 18 iters, 36 reads, 68 MFMA
            int qe = ((((base_e + 4 * c)    ) & 127) ^ m7) << 3;
            int qo = ((((base_e + 4 * c) + 2) & 127) ^ m7) << 3;
            short8v fe = *(const short8v*)&uls[i16][qe];
            short8v fo = *(const short8v*)&uls[i16][qo];
            if (c < NCH) {
                a0 = __builtin_amdgcn_mfma_f32_16x16x32_bf16(bfr[c], fe, a0, 0, 0, 0);
                a1 = __builtin_amdgcn_mfma_f32_16x16x32_bf16(bfr[c], fo, a1, 0, 0, 0);
            }
            if (c >= 1) {
                a2 = __builtin_amdgcn_mfma_f32_16x16x32_bf16(bfr[c - 1], fe, a2, 0, 0, 0);
                a3 = __builtin_amdgcn_mfma_f32_16x16x32_bf16(bfr[c - 1], fo, a3, 0, 0, 0);
            }
        }

        // ---- epilogue: lane holds y[batch=i16][Wp + 4hi + r]; trbuf transpose,
        // then asm-pinned dwordx4 stores (8 lanes x 16B contiguous = full line).
        int lc = lane & 7;
        int b0 = lane >> 3;
        int pch = lc ^ b0;
#pragma unroll
        for (int pass = 0; pass < 2; ++pass) {
            float4v va = pass ? a2 : a0;                     // l [Wp, Wp+16)
            float4v vb = pass ? a3 : a1;                     // l [Wp+16, Wp+32)
            *(float4v*)&trbuf[w][i16][((hi    ) ^ m7) << 2] = va;
            *(float4v*)&trbuf[w][i16][((4 + hi) ^ m7) << 2] = vb;
            asm volatile("s_waitcnt lgkmcnt(0)" ::: "memory");
            int Wp = W + 32 * pass;
            float4v v0 = *(const float4v*)&trbuf[w][b0][pch << 2];
            float4v v1 = *(const float4v*)&trbuf[w][b0 + 8][pch << 2];
            float* p0 = y + (long)b0 * HL + (long)h * L_DIM + Wp + lc * 4;
            float* p1 = p0 + 8 * HL;
            asm volatile("global_store_dwordx4 %0, %1, off\n\t"
                         "global_store_dwordx4 %2, %3, off"
                         :: "v"(p0), "v"(v0), "v"(p1), "v"(v1) : "memory");
            asm volatile("s_waitcnt lgkmcnt(0)" ::: "memory");
        }

        if (s < QLEN / SEGC - 1) stage_write(uls, X + SEGC, t, rn);
        __syncthreads();
    }
}

extern "C" void kernel_launch(void* const* d_in, const int* in_sizes, int n_in,
                              void* d_out, int out_size, void* d_ws, size_t ws_size,
                              hipStream_t stream) {
    const float* u   = (const float*)d_in[0];
    const float* lre = (const float*)d_in[1];
    const float* lim = (const float*)d_in[2];
    const float* Cre = (const float*)d_in[3];
    const float* Cim = (const float*)d_in[4];
    const float* D   = (const float*)d_in[5];
    float* y = (float*)d_out;

    unsigned int* Vre2 = (unsigned int*)d_ws;                 // P*M/2 uints
    unsigned int* Vim2 = Vre2 + P_DIM * (M_TR / 2);
    float*        Krp  = (float*)(Vim2 + P_DIM * (M_TR / 2)); // H*KRP floats

    vand_kernel<<<dim3(P_DIM * (M_TR / 2) / NTHR), dim3(NTHR), 0, stream>>>(lre, lim, Vre2, Vim2);
    kr_kernel<<<dim3(H_DIM / KRH), dim3(NTHR), 0, stream>>>(Cre, Cim, D, Vre2, Vim2, Krp);
    conv_mfma<<<dim3(H_DIM, L_DIM / QLEN), dim3(NTHR), 0, stream>>>(u, Krp, y);
}

// Round 10
// 149.675 us; speedup vs baseline: 1.6650x; 1.6650x over previous
//
#include <hip/hip_runtime.h>
#include <math.h>

#define P_DIM 512
#define H_DIM 512
#define L_DIM 4096
#define M_TR  512
#define NTHR  256
#define QLEN  2048          // outputs per block (grid = H x 2)
#define SEGC  256           // cols per pipeline step
#define RING  1024          // ring cols (bf16), 32KB LDS
#define KRP   576           // padded Kr row stride (zeros at [0,32) and [544,576))
#define NCH   17            // k-chunks of 32 covering [0,544)

typedef __attribute__((ext_vector_type(8))) short short8v;
typedef __attribute__((ext_vector_type(4))) float float4v;

__device__ __forceinline__ unsigned int f2bf(float f) {
    union { float f; unsigned int u; } v; v.f = f;
    return (v.u + 0x7FFFu + ((v.u >> 16) & 1u)) >> 16;   // RNE
}
__device__ __forceinline__ float bf2f(unsigned int b) {
    union { unsigned int u; float f; } v; v.u = b << 16; return v.f;
}

// Kernel A: V[p][m] = lam^m, bf16 pairs (m even|odd packed in uint).
__global__ void vand_kernel(const float* __restrict__ lre, const float* __restrict__ lim,
                            unsigned int* __restrict__ Vre2, unsigned int* __restrict__ Vim2) {
    int idx = blockIdx.x * NTHR + threadIdx.x;
    if (idx >= P_DIM * 256) return;
    int p = idx >> 8;
    int m0 = (idx & 255) * 2;
    float re = lre[p], im = lim[p];
    float logr = 0.5f * logf(re * re + im * im);
    float th = atan2f(im, re);
    float mag = expf((float)m0 * logr);
    float s, c;
    sincosf((float)m0 * th, &s, &c);
    float vr0 = mag * c, vi0 = mag * s;
    float vr1 = vr0 * re - vi0 * im;
    float vi1 = vr0 * im + vi0 * re;
    Vre2[idx] = f2bf(vr0) | (f2bf(vr1) << 16);
    Vim2[idx] = f2bf(vi0) | (f2bf(vi1) << 16);
}

// Kernel B (round-7 proven shape): Krp[h][32+m] = sum_p Cre*Vre - Cim*Vim
// (+D at m=0); zero pads at [0,32) and [544,576). 2 h per block, 256 blocks.
__global__ __launch_bounds__(NTHR) void kr_kernel(const float* __restrict__ Cre,
                                                  const float* __restrict__ Cim,
                                                  const float* __restrict__ D,
                                                  const unsigned int* __restrict__ Vre2,
                                                  const unsigned int* __restrict__ Vim2,
                                                  float* __restrict__ Krp) {
    __shared__ float cre_s[2][P_DIM];
    __shared__ float cim_s[2][P_DIM];
    int t = threadIdx.x;
    int h0 = blockIdx.x * 2;
#pragma unroll
    for (int k = 0; k < 4; ++k) {
        int i = t + k * NTHR;
        int hi = i >> 9, pp = i & (P_DIM - 1);
        cre_s[hi][pp] = Cre[(h0 + hi) * P_DIM + pp];
        cim_s[hi][pp] = Cim[(h0 + hi) * P_DIM + pp];
    }
    __syncthreads();
    float a00 = 0.f, a01 = 0.f, a10 = 0.f, a11 = 0.f;
    for (int p = 0; p < P_DIM; ++p) {
        unsigned int vr = Vre2[p * 256 + t];
        unsigned int vi = Vim2[p * 256 + t];
        float vr0 = bf2f(vr & 0xFFFFu), vr1 = bf2f(vr >> 16);
        float vi0 = bf2f(vi & 0xFFFFu), vi1 = bf2f(vi >> 16);
        float cr0 = cre_s[0][p], ci0 = cim_s[0][p];
        float cr1 = cre_s[1][p], ci1 = cim_s[1][p];
        a00 += cr0 * vr0 - ci0 * vi0;  a01 += cr0 * vr1 - ci0 * vi1;
        a10 += cr1 * vr0 - ci1 * vi0;  a11 += cr1 * vr1 - ci1 * vi1;
    }
    if (t == 0) { a00 += D[h0]; a10 += D[h0 + 1]; }
    Krp[h0 * KRP + 32 + 2 * t]           = a00;
    Krp[h0 * KRP + 32 + 2 * t + 1]       = a01;
    Krp[(h0 + 1) * KRP + 32 + 2 * t]     = a10;
    Krp[(h0 + 1) * KRP + 32 + 2 * t + 1] = a11;
    if (t < 32) {
        Krp[h0 * KRP + t] = 0.f;       Krp[h0 * KRP + 544 + t] = 0.f;
        Krp[(h0 + 1) * KRP + t] = 0.f; Krp[(h0 + 1) * KRP + 544 + t] = 0.f;
    }
}

// ---- staging helpers: one 256-col chunk, 16 batches, f32 -> bf16 into swizzled ring
__device__ __forceinline__ void stage_load(const float* __restrict__ u, int h, int CB, int t,
                                           float4* r) {
    int j = t >> 4, coff = (t & 15) << 4;
    int gl = CB + coff;
    if (gl >= 0) {
        const float* p = u + ((long)j * H_DIM + h) * L_DIM + gl;
        r[0] = *(const float4*)p;
        r[1] = *(const float4*)(p + 4);
        r[2] = *(const float4*)(p + 8);
        r[3] = *(const float4*)(p + 12);
    } else {
        r[0] = r[1] = r[2] = r[3] = make_float4(0.f, 0.f, 0.f, 0.f);
    }
}
__device__ __forceinline__ void stage_write(unsigned short (*uls)[RING], int CB, int t,
                                            const float4* r) {
    int j = t >> 4, coff = (t & 15) << 4;
    int slot = (CB + coff) & (RING - 1);
    int ch = slot >> 3;                       // even; thread owns chunks ch, ch+1
    unsigned int pk[8];
#pragma unroll
    for (int k = 0; k < 4; ++k) {
        pk[2 * k]     = f2bf(r[k].x) | (f2bf(r[k].y) << 16);
        pk[2 * k + 1] = f2bf(r[k].z) | (f2bf(r[k].w) << 16);
    }
    int sw = j & 7;
    *(uint4*)&uls[j][(ch ^ sw) << 3]       = *(const uint4*)&pk[0];
    *(uint4*)&uls[j][((ch + 1) ^ sw) << 3] = *(const uint4*)&pk[4];
}

// Kernel C (round-8 proven): ring-buffered MFMA Toeplitz convolution, 16x16x32,
// 4-tile A-reuse, swapped operands, asm-pinned full-line dwordx4 stores.
__global__ __launch_bounds__(NTHR, 4) void conv_mfma(const float* __restrict__ u,
                                                     const float* __restrict__ Krp,
                                                     float* __restrict__ y) {
    __shared__ __align__(16) unsigned short uls[16][RING];   // 32768 B
    __shared__ __align__(16) float trbuf[4][16][32];         // 8192 B  (total 40960)
    int t = threadIdx.x;
    int h = blockIdx.x;
    int Q = blockIdx.y * QLEN;
    int lane = t & 63, w = t >> 6;
    int i16 = lane & 15, hi = lane >> 4;
    int m7 = i16 & 7;
    const long HL = (long)H_DIM * L_DIM;

    // zero ring (finite values everywhere; negative-l slots stay zero)
    {
        unsigned short* flat = &uls[0][0];
        for (int i = t; i < (16 * RING) / 8; i += NTHR)
            *(uint4*)(flat + i * 8) = make_uint4(0u, 0u, 0u, 0u);
    }

    // A fragments (Toeplitz kernel): A[i][k] = Krp[544 + i - k], k = 32c + 8hi + e
    short8v bfr[NCH];
    {
        const float* kp = Krp + h * KRP + 544 + i16 - 8 * hi;
#pragma unroll
        for (int c = 0; c < NCH; ++c) {
            short8v bv;
#pragma unroll
            for (int e = 0; e < 8; ++e)
                bv[e] = (short)f2bf(kp[-32 * c - e]);
            bfr[c] = bv;
        }
    }
    __syncthreads();

    // prestage 3 chunks: u cols [Q-512, Q+256)
    {
        float4 r0[4], r1[4], r2[4];
        stage_load(u, h, Q - 512, t, r0);
        stage_load(u, h, Q - 256, t, r1);
        stage_load(u, h, Q,       t, r2);
        stage_write(uls, Q - 512, t, r0);
        stage_write(uls, Q - 256, t, r1);
        stage_write(uls, Q,       t, r2);
    }
    __syncthreads();

    for (int s = 0; s < QLEN / SEGC; ++s) {
        int X = Q + s * SEGC;
        float4 rn[4];
        if (s < QLEN / SEGC - 1) stage_load(u, h, X + SEGC, t, rn);

        int W = X + w * 64;
        int base_e = (((W - 512) & (RING - 1)) >> 3) + hi;
        float4v a0 = {0.f,0.f,0.f,0.f}, a1 = {0.f,0.f,0.f,0.f};
        float4v a2 = {0.f,0.f,0.f,0.f}, a3 = {0.f,0.f,0.f,0.f};
#pragma unroll
        for (int c = 0; c <= NCH; ++c) {                      // 18 iters, 36 reads, 68 MFMA
            int qe = ((((base_e + 4 * c)    ) & 127) ^ m7) << 3;
            int qo = ((((base_e + 4 * c) + 2) & 127) ^ m7) << 3;
            short8v fe = *(const short8v*)&uls[i16][qe];
            short8v fo = *(const short8v*)&uls[i16][qo];
            if (c < NCH) {
                a0 = __builtin_amdgcn_mfma_f32_16x16x32_bf16(bfr[c], fe, a0, 0, 0, 0);
                a1 = __builtin_amdgcn_mfma_f32_16x16x32_bf16(bfr[c], fo, a1, 0, 0, 0);
            }
            if (c >= 1) {
                a2 = __builtin_amdgcn_mfma_f32_16x16x32_bf16(bfr[c - 1], fe, a2, 0, 0, 0);
                a3 = __builtin_amdgcn_mfma_f32_16x16x32_bf16(bfr[c - 1], fo, a3, 0, 0, 0);
            }
        }

        // ---- epilogue: lane holds y[batch=i16][Wp + 4hi + r]; trbuf transpose,
        // then asm-pinned dwordx4 stores (8 lanes x 16B contiguous = full line).
        int lc = lane & 7;
        int b0 = lane >> 3;
        int pch = lc ^ b0;
#pragma unroll
        for (int pass = 0; pass < 2; ++pass) {
            float4v va = pass ? a2 : a0;                     // l [Wp, Wp+16)
            float4v vb = pass ? a3 : a1;                     // l [Wp+16, Wp+32)
            *(float4v*)&trbuf[w][i16][((hi    ) ^ m7) << 2] = va;
            *(float4v*)&trbuf[w][i16][((4 + hi) ^ m7) << 2] = vb;
            asm volatile("s_waitcnt lgkmcnt(0)" ::: "memory");
            int Wp = W + 32 * pass;
            float4v v0 = *(const float4v*)&trbuf[w][b0][pch << 2];
            float4v v1 = *(const float4v*)&trbuf[w][b0 + 8][pch << 2];
            float* p0 = y + (long)b0 * HL + (long)h * L_DIM + Wp + lc * 4;
            float* p1 = p0 + 8 * HL;
            asm volatile("global_store_dwordx4 %0, %1, off\n\t"
                         "global_store_dwordx4 %2, %3, off"
                         :: "v"(p0), "v"(v0), "v"(p1), "v"(v1) : "memory");
            asm volatile("s_waitcnt lgkmcnt(0)" ::: "memory");
        }

        if (s < QLEN / SEGC - 1) stage_write(uls, X + SEGC, t, rn);
        __syncthreads();
    }
}

extern "C" void kernel_launch(void* const* d_in, const int* in_sizes, int n_in,
                              void* d_out, int out_size, void* d_ws, size_t ws_size,
                              hipStream_t stream) {
    const float* u   = (const float*)d_in[0];
    const float* lre = (const float*)d_in[1];
    const float* lim = (const float*)d_in[2];
    const float* Cre = (const float*)d_in[3];
    const float* Cim = (const float*)d_in[4];
    const float* D   = (const float*)d_in[5];
    float* y = (float*)d_out;

    unsigned int* Vre2 = (unsigned int*)d_ws;                 // P*256 uints
    unsigned int* Vim2 = Vre2 + P_DIM * 256;
    float*        Krp  = (float*)(Vim2 + P_DIM * 256);        // H*KRP floats

    vand_kernel<<<dim3(P_DIM * 256 / NTHR), dim3(NTHR), 0, stream>>>(lre, lim, Vre2, Vim2);
    kr_kernel<<<dim3(H_DIM / 2), dim3(NTHR), 0, stream>>>(Cre, Cim, D, Vre2, Vim2, Krp);
    conv_mfma<<<dim3(H_DIM, L_DIM / QLEN), dim3(NTHR), 0, stream>>>(u, Krp, y);
}